// Round 1
// baseline (4117.194 us; speedup 1.0000x reference)
//
#include <hip/hip_runtime.h>

#define H      51
#define T_IN   512
#define T_TOT  576
#define PITCH  52
// float offsets within smem
#define OFF_W1 0                          // Whh1: 204 x 52
#define OFF_W3 (204 * PITCH)              // Wih3 gates g,o: 102 x 52
#define OFF_P  (OFF_W3 + 102 * PITCH)     // partials: [2 buf][2 elem][4 wave][52] float4
#define LDSFL  (OFF_P + 2 * 2 * 4 * PITCH * 4)  // 19,240 floats = 76,960 B -> 2 blocks/CU

__device__ __forceinline__ float bf2f(unsigned short u) {
    return __uint_as_float(((unsigned int)u) << 16);
}
__device__ __forceinline__ unsigned short f2bf(float f) {
    unsigned int u = __float_as_uint(f);
    u += 0x7fffu + ((u >> 16) & 1u);
    return (unsigned short)(u >> 16);
}
__device__ __forceinline__ float wget(const void* p, int i, bool is16) {
    return is16 ? bf2f(((const unsigned short*)p)[i]) : ((const float*)p)[i];
}
__device__ __forceinline__ float rl(float v, int k) {
    return __uint_as_float((unsigned int)__builtin_amdgcn_readlane((int)__float_as_uint(v), k));
}
__device__ __forceinline__ float sigm(float x) {
    x = fminf(fmaxf(x, -30.f), 30.f);
    return 1.f / (1.f + __expf(-x));
}
__device__ __forceinline__ float tanh_f(float x) {
    x = fminf(fmaxf(x, -15.f), 15.f);
    float e = __expf(2.f * x);
    return (e - 1.f) / (e + 1.f);
}
__device__ __forceinline__ float f4e(float4 v, int i) {
    return i == 0 ? v.x : i == 1 ? v.y : i == 2 ? v.z : v.w;
}

#define L13(M) M(0) M(1) M(2) M(3) M(4) M(5) M(6) M(7) M(8) M(9) M(10) M(11) M(12)

#define RED(sv) { sv += __shfl_xor(sv, 32, 64); sv += __shfl_xor(sv, 16, 64); \
    sv += __shfl_xor(sv, 8, 64); sv += __shfl_xor(sv, 4, 64); \
    sv += __shfl_xor(sv, 2, 64); sv += __shfl_xor(sv, 1, 64); }

// 512 blocks x 4 waves; block = 2 batch elements. Wave w owns k-slice 13w..13w+12
// of the register matrices (Wih2, Whh2, Whh3, Wih3 i+f: 182 regs/lane) and an
// aligned k-slice of the LDS matrices (Whh1, Wih3 g/o).
// Exchange restructure vs previous version: ONE barrier per layer (3/timestep
// instead of 6). All 4 waves redundantly reduce the 4 partial rows, fold
// bias (+x for layer 1), and run the cell update, keeping h per-lane in
// registers -- no hbuf round-trip, no idle waves during UPD, symmetric roles.
// WAR across phases handled by double-buffered partial bufs (toggle per phase).
extern "C" __global__ void __launch_bounds__(256, 2)
lstm3_kernel(const void* g_in,  const void* g_Wih1, const void* g_Whh1,
             const void* g_bih1, const void* g_bhh1,
             const void* g_Wih2, const void* g_Whh2, const void* g_bih2, const void* g_bhh2,
             const void* g_Wih3, const void* g_Whh3, const void* g_bih3, const void* g_bhh3,
             const void* g_Wlin, const void* g_blin, void* g_out)
{
    extern __shared__ float smem[];

    const int tid  = threadIdx.x;
    const int lane = tid & 63;
    const int wid  = tid >> 6;
    const int eb   = blockIdx.x * 2;
    const int jeff = (lane < H) ? lane : (H - 1);

    // ---- dtype sniff (proven: resolves fp32 on this harness)
    bool is16 = true;
    {
        const unsigned short* p = (const unsigned short*)g_Wih1;
        for (int i = 0; i < 204; ++i) {
            float v = fabsf(bf2f(p[i]));
            if (!(v < 0.2f)) is16 = false;
        }
    }

    // ---- LDS staging
    for (int i = tid; i < 204 * PITCH; i += 256) {
        int r = i / PITCH, k = i - r * PITCH;
        smem[OFF_W1 + i] = (k < H) ? wget(g_Whh1, r * H + k, is16) : 0.f;
    }
    for (int i = tid; i < 102 * PITCH; i += 256) {
        int r = i / PITCH, k = i - r * PITCH;
        smem[OFF_W3 + i] = (k < H) ? wget(g_Wih3, (2 * H + r) * H + k, is16) : 0.f;
    }
    __syncthreads();

    const int kbR = 13 * wid;                                   // register k-slice
    const int kbL = (wid == 0) ? 0 : (wid == 1) ? 12 : (wid == 2) ? 28 : 40;
    const int nbL = (wid == 1) ? 4 : 3;                         // float4 blocks in LDS slice

#define WC(srcp, row, kk) (((kbR + (kk)) < H) ? wget(srcp, (row) * H + kbR + (kk), is16) : 0.f)
#define DECL13(p) float p##_0,p##_1,p##_2,p##_3,p##_4,p##_5,p##_6,p##_7,p##_8,p##_9,p##_10,p##_11,p##_12;
#define LOAD13(p, srcp, row) \
    p##_0 = WC(srcp, row, 0);  p##_1 = WC(srcp, row, 1);  p##_2 = WC(srcp, row, 2); \
    p##_3 = WC(srcp, row, 3);  p##_4 = WC(srcp, row, 4);  p##_5 = WC(srcp, row, 5); \
    p##_6 = WC(srcp, row, 6);  p##_7 = WC(srcp, row, 7);  p##_8 = WC(srcp, row, 8); \
    p##_9 = WC(srcp, row, 9);  p##_10 = WC(srcp, row, 10); p##_11 = WC(srcp, row, 11); \
    p##_12 = WC(srcp, row, 12);

    DECL13(wih2g0) DECL13(wih2g1) DECL13(wih2g2) DECL13(wih2g3)
    DECL13(whh2g0) DECL13(whh2g1) DECL13(whh2g2) DECL13(whh2g3)
    DECL13(whh3g0) DECL13(whh3g1) DECL13(whh3g2) DECL13(whh3g3)
    DECL13(wih3i)  DECL13(wih3f)
    LOAD13(wih2g0, g_Wih2, 0 * H + jeff) LOAD13(wih2g1, g_Wih2, 1 * H + jeff)
    LOAD13(wih2g2, g_Wih2, 2 * H + jeff) LOAD13(wih2g3, g_Wih2, 3 * H + jeff)
    LOAD13(whh2g0, g_Whh2, 0 * H + jeff) LOAD13(whh2g1, g_Whh2, 1 * H + jeff)
    LOAD13(whh2g2, g_Whh2, 2 * H + jeff) LOAD13(whh2g3, g_Whh2, 3 * H + jeff)
    LOAD13(whh3g0, g_Whh3, 0 * H + jeff) LOAD13(whh3g1, g_Whh3, 1 * H + jeff)
    LOAD13(whh3g2, g_Whh3, 2 * H + jeff) LOAD13(whh3g3, g_Whh3, 3 * H + jeff)
    LOAD13(wih3i,  g_Wih3, 0 * H + jeff)
    LOAD13(wih3f,  g_Wih3, 1 * H + jeff)

    const float b1_0 = wget(g_bih1, 0*H+jeff, is16) + wget(g_bhh1, 0*H+jeff, is16);
    const float b1_1 = wget(g_bih1, 1*H+jeff, is16) + wget(g_bhh1, 1*H+jeff, is16);
    const float b1_2 = wget(g_bih1, 2*H+jeff, is16) + wget(g_bhh1, 2*H+jeff, is16);
    const float b1_3 = wget(g_bih1, 3*H+jeff, is16) + wget(g_bhh1, 3*H+jeff, is16);
    const float b2_0 = wget(g_bih2, 0*H+jeff, is16) + wget(g_bhh2, 0*H+jeff, is16);
    const float b2_1 = wget(g_bih2, 1*H+jeff, is16) + wget(g_bhh2, 1*H+jeff, is16);
    const float b2_2 = wget(g_bih2, 2*H+jeff, is16) + wget(g_bhh2, 2*H+jeff, is16);
    const float b2_3 = wget(g_bih2, 3*H+jeff, is16) + wget(g_bhh2, 3*H+jeff, is16);
    const float b3_0 = wget(g_bih3, 0*H+jeff, is16) + wget(g_bhh3, 0*H+jeff, is16);
    const float b3_1 = wget(g_bih3, 1*H+jeff, is16) + wget(g_bhh3, 1*H+jeff, is16);
    const float b3_2 = wget(g_bih3, 2*H+jeff, is16) + wget(g_bhh3, 2*H+jeff, is16);
    const float b3_3 = wget(g_bih3, 3*H+jeff, is16) + wget(g_bhh3, 3*H+jeff, is16);
    const float wi1_0 = wget(g_Wih1, 0*H+jeff, is16);
    const float wi1_1 = wget(g_Wih1, 1*H+jeff, is16);
    const float wi1_2 = wget(g_Wih1, 2*H+jeff, is16);
    const float wi1_3 = wget(g_Wih1, 3*H+jeff, is16);
    const float wlinr = (lane < H) ? wget(g_Wlin, lane, is16) : 0.f;
    const float blinr = wget(g_blin, 0, is16);

    const float4* A1g0 = (const float4*)(smem + OFF_W1 + (0*H + jeff) * PITCH + kbL);
    const float4* A1g1 = (const float4*)(smem + OFF_W1 + (1*H + jeff) * PITCH + kbL);
    const float4* A1g2 = (const float4*)(smem + OFF_W1 + (2*H + jeff) * PITCH + kbL);
    const float4* A1g3 = (const float4*)(smem + OFF_W1 + (3*H + jeff) * PITCH + kbL);
    const float4* A3g  = (const float4*)(smem + OFF_W3 + (      jeff) * PITCH + kbL);
    const float4* A3o  = (const float4*)(smem + OFF_W3 + (H   + jeff) * PITCH + kbL);
    float4* pb = (float4*)(smem + OFF_P);

    float h1_0=0.f,h1_1=0.f,h2_0=0.f,h2_1=0.f,h3_0=0.f,h3_1=0.f;
    float c1_0=0.f,c1_1=0.f,c2_0=0.f,c2_1=0.f,c3_0=0.f,c3_1=0.f;   // redundant in all waves
    float xf0=0.f,xf1=0.f;                                          // redundant in all waves
    int pbuf = 0;

    const unsigned short* in16 = (const unsigned short*)g_in;
    const float*          in32 = (const float*)g_in;
    unsigned short* o16w0 = (unsigned short*)g_out + (size_t)(eb+0)*T_TOT;
    unsigned short* o16w1 = (unsigned short*)g_out + (size_t)(eb+1)*T_TOT;
    float* o32w0 = (float*)g_out + (size_t)(eb+0)*T_TOT;
    float* o32w1 = (float*)g_out + (size_t)(eb+1)*T_TOT;

#define P2(kk) { \
    float s0_ = rl(h1_0, kbR+(kk)), s1_ = rl(h1_1, kbR+(kk)); \
    float r0_ = rl(h2_0, kbR+(kk)), r1_ = rl(h2_1, kbR+(kk)); \
    a0_0=fmaf(wih2g0_##kk,s0_,a0_0); a0_1=fmaf(wih2g0_##kk,s1_,a0_1); \
    a1_0=fmaf(wih2g1_##kk,s0_,a1_0); a1_1=fmaf(wih2g1_##kk,s1_,a1_1); \
    a2_0=fmaf(wih2g2_##kk,s0_,a2_0); a2_1=fmaf(wih2g2_##kk,s1_,a2_1); \
    a3_0=fmaf(wih2g3_##kk,s0_,a3_0); a3_1=fmaf(wih2g3_##kk,s1_,a3_1); \
    a0_0=fmaf(whh2g0_##kk,r0_,a0_0); a0_1=fmaf(whh2g0_##kk,r1_,a0_1); \
    a1_0=fmaf(whh2g1_##kk,r0_,a1_0); a1_1=fmaf(whh2g1_##kk,r1_,a1_1); \
    a2_0=fmaf(whh2g2_##kk,r0_,a2_0); a2_1=fmaf(whh2g2_##kk,r1_,a2_1); \
    a3_0=fmaf(whh2g3_##kk,r0_,a3_0); a3_1=fmaf(whh2g3_##kk,r1_,a3_1); }

#define P3(kk) { \
    float s0_ = rl(h2_0, kbR+(kk)), s1_ = rl(h2_1, kbR+(kk)); \
    float r0_ = rl(h3_0, kbR+(kk)), r1_ = rl(h3_1, kbR+(kk)); \
    a0_0=fmaf(wih3i_##kk,s0_,a0_0);  a0_1=fmaf(wih3i_##kk,s1_,a0_1); \
    a1_0=fmaf(wih3f_##kk,s0_,a1_0);  a1_1=fmaf(wih3f_##kk,s1_,a1_1); \
    a0_0=fmaf(whh3g0_##kk,r0_,a0_0); a0_1=fmaf(whh3g0_##kk,r1_,a0_1); \
    a1_0=fmaf(whh3g1_##kk,r0_,a1_0); a1_1=fmaf(whh3g1_##kk,r1_,a1_1); \
    a2_0=fmaf(whh3g2_##kk,r0_,a2_0); a2_1=fmaf(whh3g2_##kk,r1_,a2_1); \
    a3_0=fmaf(whh3g3_##kk,r0_,a3_0); a3_1=fmaf(whh3g3_##kk,r1_,a3_1); }

    // write my partial rows for both elems; ONE barrier
#define WRPART() { \
    if (lane < H) { \
        int wb_ = (pbuf*8 + wid) * PITCH + lane; \
        pb[wb_]           = make_float4(a0_0, a1_0, a2_0, a3_0); \
        pb[wb_ + 4*PITCH] = make_float4(a0_1, a1_1, a2_1, a3_1); \
    } \
    __syncthreads(); }

    // all waves redundantly: sum 4 partial rows, fold bias/x, cell update.
    // h stays per-lane in registers (identical across waves by construction).
#define REDUPD(cm0, cm1, hv0, hv1, e00,e01,e02,e03, e10,e11,e12,e13) { \
    int rb_ = pbuf*8*PITCH + jeff; \
    float4 qa_ = pb[rb_];           float4 qb_ = pb[rb_ + 1*PITCH]; \
    float4 qc_ = pb[rb_ + 2*PITCH]; float4 qd_ = pb[rb_ + 3*PITCH]; \
    float4 ua_ = pb[rb_ + 4*PITCH]; float4 ub_ = pb[rb_ + 5*PITCH]; \
    float4 uc_ = pb[rb_ + 6*PITCH]; float4 ud_ = pb[rb_ + 7*PITCH]; \
    float gi0_ = qa_.x+qb_.x+qc_.x+qd_.x + (e00); \
    float gf0_ = qa_.y+qb_.y+qc_.y+qd_.y + (e01); \
    float gg0_ = qa_.z+qb_.z+qc_.z+qd_.z + (e02); \
    float go0_ = qa_.w+qb_.w+qc_.w+qd_.w + (e03); \
    float gi1_ = ua_.x+ub_.x+uc_.x+ud_.x + (e10); \
    float gf1_ = ua_.y+ub_.y+uc_.y+ud_.y + (e11); \
    float gg1_ = ua_.z+ub_.z+uc_.z+ud_.z + (e12); \
    float go1_ = ua_.w+ub_.w+uc_.w+ud_.w + (e13); \
    float i0_ = sigm(gi0_), f0_ = sigm(gf0_), g0_ = tanh_f(gg0_), o0_ = sigm(go0_); \
    cm0 = f0_ * cm0 + i0_ * g0_; \
    hv0 = o0_ * tanh_f(cm0); \
    float i1_ = sigm(gi1_), f1_ = sigm(gf1_), g1_ = tanh_f(gg1_), o1_ = sigm(go1_); \
    cm1 = f1_ * cm1 + i1_ * g1_; \
    hv1 = o1_ * tanh_f(cm1); \
    pbuf ^= 1; }

#pragma clang loop unroll(disable)
    for (int t = 0; t < T_TOT; ++t) {
        float a0_0,a1_0,a2_0,a3_0,a0_1,a1_1,a2_1,a3_1;

        // x for this timestep (issued early; consumed after L1 barrier)
        float x0, x1;
        if (t < T_IN) {
            if (is16) {
                x0 = bf2f(in16[(size_t)(eb+0)*T_IN + t]);
                x1 = bf2f(in16[(size_t)(eb+1)*T_IN + t]);
            } else {
                x0 = in32[(size_t)(eb+0)*T_IN + t];
                x1 = in32[(size_t)(eb+1)*T_IN + t];
            }
        } else { x0 = xf0; x1 = xf1; }

        // ---------------- layer 1: Whh1 slice from LDS ----------------
        a0_0=a1_0=a2_0=a3_0=a0_1=a1_1=a2_1=a3_1=0.f;
        for (int b = 0; b < nbL; ++b) {
            float4 u0 = A1g0[b], u1 = A1g1[b], u2 = A1g2[b], u3 = A1g3[b];
#pragma unroll
            for (int i = 0; i < 4; ++i) {
                int k = kbL + 4*b + i;
                float s0 = rl(h1_0, k), s1 = rl(h1_1, k);
                a0_0 = fmaf(f4e(u0,i), s0, a0_0); a0_1 = fmaf(f4e(u0,i), s1, a0_1);
                a1_0 = fmaf(f4e(u1,i), s0, a1_0); a1_1 = fmaf(f4e(u1,i), s1, a1_1);
                a2_0 = fmaf(f4e(u2,i), s0, a2_0); a2_1 = fmaf(f4e(u2,i), s1, a2_1);
                a3_0 = fmaf(f4e(u3,i), s0, a3_0); a3_1 = fmaf(f4e(u3,i), s1, a3_1);
            }
        }
        WRPART()
        REDUPD(c1_0, c1_1, h1_0, h1_1,
               fmaf(wi1_0,x0,b1_0), fmaf(wi1_1,x0,b1_1), fmaf(wi1_2,x0,b1_2), fmaf(wi1_3,x0,b1_3),
               fmaf(wi1_0,x1,b1_0), fmaf(wi1_1,x1,b1_1), fmaf(wi1_2,x1,b1_2), fmaf(wi1_3,x1,b1_3))

        // ---------------- layer 2: all-register ----------------
        a0_0=a1_0=a2_0=a3_0=a0_1=a1_1=a2_1=a3_1=0.f;
        L13(P2)
        WRPART()
        REDUPD(c2_0, c2_1, h2_0, h2_1, b2_0,b2_1,b2_2,b2_3, b2_0,b2_1,b2_2,b2_3)

        // ---------------- layer 3: regs (i,f + Whh3) + LDS (g,o) ----------------
        a0_0=a1_0=a2_0=a3_0=a0_1=a1_1=a2_1=a3_1=0.f;
        L13(P3)
        for (int b = 0; b < nbL; ++b) {
            float4 ug = A3g[b], uo = A3o[b];
#pragma unroll
            for (int i = 0; i < 4; ++i) {
                int k = kbL + 4*b + i;
                float s0 = rl(h2_0, k), s1 = rl(h2_1, k);
                a2_0 = fmaf(f4e(ug,i), s0, a2_0); a2_1 = fmaf(f4e(ug,i), s1, a2_1);
                a3_0 = fmaf(f4e(uo,i), s0, a3_0); a3_1 = fmaf(f4e(uo,i), s1, a3_1);
            }
        }
        WRPART()
        REDUPD(c3_0, c3_1, h3_0, h3_1, b3_0,b3_1,b3_2,b3_3, b3_0,b3_1,b3_2,b3_3)

        // ---------------- head: all waves redundantly ----------------
        float s0 = wlinr * h3_0; RED(s0) float ov0 = s0 + blinr;
        float s1 = wlinr * h3_1; RED(s1) float ov1 = s1 + blinr;
        xf0 = ov0; xf1 = ov1;
        if (wid == 0 && lane == 0) {
            if (is16) { o16w0[t] = f2bf(ov0); o16w1[t] = f2bf(ov1); }
            else      { o32w0[t] = ov0;       o32w1[t] = ov1; }
        }
    }
}

extern "C" void kernel_launch(void* const* d_in, const int* in_sizes, int n_in,
                              void* d_out, int out_size, void* d_ws, size_t ws_size,
                              hipStream_t stream) {
    (void)in_sizes; (void)n_in; (void)d_ws; (void)ws_size; (void)out_size;
    size_t shmem = LDSFL * sizeof(float);   // 76,960 B -> 2 blocks/CU
    hipFuncSetAttribute((const void*)lstm3_kernel,
                        hipFuncAttributeMaxDynamicSharedMemorySize, (int)shmem);
    lstm3_kernel<<<dim3(512), dim3(256), shmem, stream>>>(
        d_in[0],  d_in[1],  d_in[2],  d_in[3],  d_in[4],
        d_in[5],  d_in[6],  d_in[7],  d_in[8],
        d_in[9],  d_in[10], d_in[11], d_in[12],
        d_in[13], d_in[14], d_out);
}

// Round 2
// 3061.662 us; speedup vs baseline: 1.3448x; 1.3448x over previous
//
#include <hip/hip_runtime.h>

#define H      51
#define T_IN   512
#define T_TOT  576
#define PITCH  52
// float offsets within smem
#define OFF_W1 0                          // Whh1: 204 x 52
#define OFF_W3 (204 * PITCH)              // Wih3 gates f,g,o: 153 x 52
#define OFF_P  (OFF_W3 + 153 * PITCH)     // partial buf: [2 elem][4 wave][52] float4
#define OFF_H  (OFF_P + 2 * 4 * PITCH * 4)// h broadcast: [2 elem][52] float
#define LDSFL  (OFF_H + 2 * PITCH)        // 20,332 floats = 81,328 B (2 blocks/CU)

__device__ __forceinline__ float bf2f(unsigned short u) {
    return __uint_as_float(((unsigned int)u) << 16);
}
__device__ __forceinline__ unsigned short f2bf(float f) {
    unsigned int u = __float_as_uint(f);
    u += 0x7fffu + ((u >> 16) & 1u);
    return (unsigned short)(u >> 16);
}
__device__ __forceinline__ float wget(const void* p, int i, bool is16) {
    return is16 ? bf2f(((const unsigned short*)p)[i]) : ((const float*)p)[i];
}
__device__ __forceinline__ float rl(float v, int k) {
    return __uint_as_float((unsigned int)__builtin_amdgcn_readlane((int)__float_as_uint(v), k));
}
__device__ __forceinline__ float sigm(float x) {
    x = fminf(fmaxf(x, -30.f), 30.f);
    return 1.f / (1.f + __expf(-x));
}
__device__ __forceinline__ float tanh_f(float x) {
    x = fminf(fmaxf(x, -15.f), 15.f);
    float e = __expf(2.f * x);
    return (e - 1.f) / (e + 1.f);
}
__device__ __forceinline__ float f4e(float4 v, int i) {
    return i == 0 ? v.x : i == 1 ? v.y : i == 2 ? v.z : v.w;
}

#define L13(M) M(0) M(1) M(2) M(3) M(4) M(5) M(6) M(7) M(8) M(9) M(10) M(11) M(12)

#define RED(sv) { sv += __shfl_xor(sv, 32, 64); sv += __shfl_xor(sv, 16, 64); \
    sv += __shfl_xor(sv, 8, 64); sv += __shfl_xor(sv, 4, 64); \
    sv += __shfl_xor(sv, 2, 64); sv += __shfl_xor(sv, 1, 64); }

// 512 blocks x 4 waves; block = 2 batch elements. Wave w owns k-slice 13w..13w+12
// of the register matrices (Wih2, Whh2, Whh3, Wih3-gate-i: 169 regs/lane) and an
// aligned k-slice of the LDS matrices (Whh1, Wih3 f/g/o). Partials for 4 gates x
// 2 elems exchanged via one LDS buffer; waves 0/2 do the UPD for elem 0/1 and
// rebroadcast h via LDS; wave 3 does input/bias/head/store.
//
// OCCUPANCY/VGPR NOTE (round 2): LDS = 81,328 B caps the CU at 2 blocks =
// 2 waves/SIMD regardless of registers. With __launch_bounds__(256,2) the
// allocator still targeted 4 waves/EU and capped at 128 VGPRs, spilling the
// ~169 "register-resident" weight values to scratch (seen as ~2.6 MB/dispatch
// of non-output WRITE_SIZE). amdgpu_waves_per_eu(2,2) tells it to optimize for
// exactly the occupancy LDS permits -> full 256-VGPR budget, no spills.
extern "C" __global__ void __launch_bounds__(256)
__attribute__((amdgpu_waves_per_eu(2, 2)))
lstm3_kernel(const void* g_in,  const void* g_Wih1, const void* g_Whh1,
             const void* g_bih1, const void* g_bhh1,
             const void* g_Wih2, const void* g_Whh2, const void* g_bih2, const void* g_bhh2,
             const void* g_Wih3, const void* g_Whh3, const void* g_bih3, const void* g_bhh3,
             const void* g_Wlin, const void* g_blin, void* g_out)
{
    extern __shared__ float smem[];

    const int tid  = threadIdx.x;
    const int lane = tid & 63;
    const int wid  = tid >> 6;
    const int eb   = blockIdx.x * 2;
    const int jeff = (lane < H) ? lane : (H - 1);

    // ---- dtype sniff (proven: resolves fp32 on this harness)
    bool is16 = true;
    {
        const unsigned short* p = (const unsigned short*)g_Wih1;
        for (int i = 0; i < 204; ++i) {
            float v = fabsf(bf2f(p[i]));
            if (!(v < 0.2f)) is16 = false;
        }
    }

    // ---- LDS staging
    for (int i = tid; i < 204 * PITCH; i += 256) {
        int r = i / PITCH, k = i - r * PITCH;
        smem[OFF_W1 + i] = (k < H) ? wget(g_Whh1, r * H + k, is16) : 0.f;
    }
    for (int i = tid; i < 153 * PITCH; i += 256) {
        int r = i / PITCH, k = i - r * PITCH;
        smem[OFF_W3 + i] = (k < H) ? wget(g_Wih3, (H + r) * H + k, is16) : 0.f;
    }
    __syncthreads();

    const int kbR = 13 * wid;                                   // register k-slice
    const int kbL = (wid == 0) ? 0 : (wid == 1) ? 12 : (wid == 2) ? 28 : 40;
    const int nbL = (wid == 1) ? 4 : 3;                         // float4 blocks in LDS slice

#define WC(srcp, row, kk) (((kbR + (kk)) < H) ? wget(srcp, (row) * H + kbR + (kk), is16) : 0.f)
#define DECL13(p) float p##_0,p##_1,p##_2,p##_3,p##_4,p##_5,p##_6,p##_7,p##_8,p##_9,p##_10,p##_11,p##_12;
#define LOAD13(p, srcp, row) \
    p##_0 = WC(srcp, row, 0);  p##_1 = WC(srcp, row, 1);  p##_2 = WC(srcp, row, 2); \
    p##_3 = WC(srcp, row, 3);  p##_4 = WC(srcp, row, 4);  p##_5 = WC(srcp, row, 5); \
    p##_6 = WC(srcp, row, 6);  p##_7 = WC(srcp, row, 7);  p##_8 = WC(srcp, row, 8); \
    p##_9 = WC(srcp, row, 9);  p##_10 = WC(srcp, row, 10); p##_11 = WC(srcp, row, 11); \
    p##_12 = WC(srcp, row, 12);

    DECL13(wih2g0) DECL13(wih2g1) DECL13(wih2g2) DECL13(wih2g3)
    DECL13(whh2g0) DECL13(whh2g1) DECL13(whh2g2) DECL13(whh2g3)
    DECL13(whh3g0) DECL13(whh3g1) DECL13(whh3g2) DECL13(whh3g3)
    DECL13(wih3i)
    LOAD13(wih2g0, g_Wih2, 0 * H + jeff) LOAD13(wih2g1, g_Wih2, 1 * H + jeff)
    LOAD13(wih2g2, g_Wih2, 2 * H + jeff) LOAD13(wih2g3, g_Wih2, 3 * H + jeff)
    LOAD13(whh2g0, g_Whh2, 0 * H + jeff) LOAD13(whh2g1, g_Whh2, 1 * H + jeff)
    LOAD13(whh2g2, g_Whh2, 2 * H + jeff) LOAD13(whh2g3, g_Whh2, 3 * H + jeff)
    LOAD13(whh3g0, g_Whh3, 0 * H + jeff) LOAD13(whh3g1, g_Whh3, 1 * H + jeff)
    LOAD13(whh3g2, g_Whh3, 2 * H + jeff) LOAD13(whh3g3, g_Whh3, 3 * H + jeff)
    LOAD13(wih3i,  g_Wih3, 0 * H + jeff)

    const float b1_0 = wget(g_bih1, 0*H+jeff, is16) + wget(g_bhh1, 0*H+jeff, is16);
    const float b1_1 = wget(g_bih1, 1*H+jeff, is16) + wget(g_bhh1, 1*H+jeff, is16);
    const float b1_2 = wget(g_bih1, 2*H+jeff, is16) + wget(g_bhh1, 2*H+jeff, is16);
    const float b1_3 = wget(g_bih1, 3*H+jeff, is16) + wget(g_bhh1, 3*H+jeff, is16);
    const float b2_0 = wget(g_bih2, 0*H+jeff, is16) + wget(g_bhh2, 0*H+jeff, is16);
    const float b2_1 = wget(g_bih2, 1*H+jeff, is16) + wget(g_bhh2, 1*H+jeff, is16);
    const float b2_2 = wget(g_bih2, 2*H+jeff, is16) + wget(g_bhh2, 2*H+jeff, is16);
    const float b2_3 = wget(g_bih2, 3*H+jeff, is16) + wget(g_bhh2, 3*H+jeff, is16);
    const float b3_0 = wget(g_bih3, 0*H+jeff, is16) + wget(g_bhh3, 0*H+jeff, is16);
    const float b3_1 = wget(g_bih3, 1*H+jeff, is16) + wget(g_bhh3, 1*H+jeff, is16);
    const float b3_2 = wget(g_bih3, 2*H+jeff, is16) + wget(g_bhh3, 2*H+jeff, is16);
    const float b3_3 = wget(g_bih3, 3*H+jeff, is16) + wget(g_bhh3, 3*H+jeff, is16);
    const float wi1_0 = wget(g_Wih1, 0*H+jeff, is16);
    const float wi1_1 = wget(g_Wih1, 1*H+jeff, is16);
    const float wi1_2 = wget(g_Wih1, 2*H+jeff, is16);
    const float wi1_3 = wget(g_Wih1, 3*H+jeff, is16);
    const float wlinr = (lane < H) ? wget(g_Wlin, lane, is16) : 0.f;
    const float blinr = wget(g_blin, 0, is16);

    const float4* A1g0 = (const float4*)(smem + OFF_W1 + (0*H + jeff) * PITCH + kbL);
    const float4* A1g1 = (const float4*)(smem + OFF_W1 + (1*H + jeff) * PITCH + kbL);
    const float4* A1g2 = (const float4*)(smem + OFF_W1 + (2*H + jeff) * PITCH + kbL);
    const float4* A1g3 = (const float4*)(smem + OFF_W1 + (3*H + jeff) * PITCH + kbL);
    const float4* A3f  = (const float4*)(smem + OFF_W3 + (      jeff) * PITCH + kbL);
    const float4* A3g  = (const float4*)(smem + OFF_W3 + (H   + jeff) * PITCH + kbL);
    const float4* A3o  = (const float4*)(smem + OFF_W3 + (2*H + jeff) * PITCH + kbL);
    float4* ebufP = (float4*)(smem + OFF_P);
    float*  hbuf  = smem + OFF_H;

    float h1_0=0.f,h1_1=0.f,h2_0=0.f,h2_1=0.f,h3_0=0.f,h3_1=0.f;
    float c1my=0.f,c2my=0.f,c3my=0.f;      // live in waves 0/2 only
    float xf0=0.f,xf1=0.f;                 // wave 3 only

    const unsigned short* in16 = (const unsigned short*)g_in;
    const float*          in32 = (const float*)g_in;
    unsigned short* o16w0 = (unsigned short*)g_out + (size_t)(eb+0)*T_TOT;
    unsigned short* o16w1 = (unsigned short*)g_out + (size_t)(eb+1)*T_TOT;
    float* o32w0 = (float*)g_out + (size_t)(eb+0)*T_TOT;
    float* o32w1 = (float*)g_out + (size_t)(eb+1)*T_TOT;

#define P2(kk) { \
    float s0_ = rl(h1_0, kbR+(kk)), s1_ = rl(h1_1, kbR+(kk)); \
    float r0_ = rl(h2_0, kbR+(kk)), r1_ = rl(h2_1, kbR+(kk)); \
    a0_0=fmaf(wih2g0_##kk,s0_,a0_0); a0_1=fmaf(wih2g0_##kk,s1_,a0_1); \
    a1_0=fmaf(wih2g1_##kk,s0_,a1_0); a1_1=fmaf(wih2g1_##kk,s1_,a1_1); \
    a2_0=fmaf(wih2g2_##kk,s0_,a2_0); a2_1=fmaf(wih2g2_##kk,s1_,a2_1); \
    a3_0=fmaf(wih2g3_##kk,s0_,a3_0); a3_1=fmaf(wih2g3_##kk,s1_,a3_1); \
    a0_0=fmaf(whh2g0_##kk,r0_,a0_0); a0_1=fmaf(whh2g0_##kk,r1_,a0_1); \
    a1_0=fmaf(whh2g1_##kk,r0_,a1_0); a1_1=fmaf(whh2g1_##kk,r1_,a1_1); \
    a2_0=fmaf(whh2g2_##kk,r0_,a2_0); a2_1=fmaf(whh2g2_##kk,r1_,a2_1); \
    a3_0=fmaf(whh2g3_##kk,r0_,a3_0); a3_1=fmaf(whh2g3_##kk,r1_,a3_1); }

#define P3(kk) { \
    float s0_ = rl(h2_0, kbR+(kk)), s1_ = rl(h2_1, kbR+(kk)); \
    float r0_ = rl(h3_0, kbR+(kk)), r1_ = rl(h3_1, kbR+(kk)); \
    a0_0=fmaf(wih3i_##kk,s0_,a0_0);  a0_1=fmaf(wih3i_##kk,s1_,a0_1); \
    a0_0=fmaf(whh3g0_##kk,r0_,a0_0); a0_1=fmaf(whh3g0_##kk,r1_,a0_1); \
    a1_0=fmaf(whh3g1_##kk,r0_,a1_0); a1_1=fmaf(whh3g1_##kk,r1_,a1_1); \
    a2_0=fmaf(whh3g2_##kk,r0_,a2_0); a2_1=fmaf(whh3g2_##kk,r1_,a2_1); \
    a3_0=fmaf(whh3g3_##kk,r0_,a3_0); a3_1=fmaf(whh3g3_##kk,r1_,a3_1); }

    // exchange partials; waves 0/2 reduce+UPD for elem 0/1; h rebroadcast via LDS
#define EXCHL(hv0, hv1, cmy) { \
    if (lane < H) { \
        ebufP[(0*4 + wid)*PITCH + lane] = make_float4(a0_0, a1_0, a2_0, a3_0); \
        ebufP[(1*4 + wid)*PITCH + lane] = make_float4(a0_1, a1_1, a2_1, a3_1); \
    } \
    __syncthreads(); \
    if ((wid & 1) == 0) { \
        const float4* pb_ = ebufP + (wid >> 1) * 4 * PITCH; \
        float4 q_ = pb_[0*PITCH + jeff]; \
        float4 t_ = pb_[1*PITCH + jeff]; q_.x+=t_.x; q_.y+=t_.y; q_.z+=t_.z; q_.w+=t_.w; \
        t_ = pb_[2*PITCH + jeff]; q_.x+=t_.x; q_.y+=t_.y; q_.z+=t_.z; q_.w+=t_.w; \
        t_ = pb_[3*PITCH + jeff]; q_.x+=t_.x; q_.y+=t_.y; q_.z+=t_.z; q_.w+=t_.w; \
        float ig_ = sigm(q_.x), fg_ = sigm(q_.y), gg_ = tanh_f(q_.z), og_ = sigm(q_.w); \
        cmy = fg_ * cmy + ig_ * gg_; \
        float hn_ = og_ * tanh_f(cmy); \
        if (lane < H) hbuf[(wid >> 1) * PITCH + lane] = hn_; \
    } \
    __syncthreads(); \
    hv0 = hbuf[0*PITCH + jeff]; \
    hv1 = hbuf[1*PITCH + jeff]; }

#pragma clang loop unroll(disable)
    for (int t = 0; t < T_TOT; ++t) {
        float a0_0,a1_0,a2_0,a3_0,a0_1,a1_1,a2_1,a3_1;

        // ---------------- layer 1 ----------------
        if (wid == 3) {
            float x0, x1;
            if (t < T_IN) {
                if (is16) {
                    x0 = bf2f(in16[(size_t)(eb+0)*T_IN + t]);
                    x1 = bf2f(in16[(size_t)(eb+1)*T_IN + t]);
                } else {
                    x0 = in32[(size_t)(eb+0)*T_IN + t];
                    x1 = in32[(size_t)(eb+1)*T_IN + t];
                }
            } else { x0 = xf0; x1 = xf1; }
            a0_0 = fmaf(wi1_0, x0, b1_0); a0_1 = fmaf(wi1_0, x1, b1_0);
            a1_0 = fmaf(wi1_1, x0, b1_1); a1_1 = fmaf(wi1_1, x1, b1_1);
            a2_0 = fmaf(wi1_2, x0, b1_2); a2_1 = fmaf(wi1_2, x1, b1_2);
            a3_0 = fmaf(wi1_3, x0, b1_3); a3_1 = fmaf(wi1_3, x1, b1_3);
        } else {
            a0_0=a1_0=a2_0=a3_0=a0_1=a1_1=a2_1=a3_1=0.f;
        }
        for (int b = 0; b < nbL; ++b) {
            float4 u0 = A1g0[b], u1 = A1g1[b], u2 = A1g2[b], u3 = A1g3[b];
#pragma unroll
            for (int i = 0; i < 4; ++i) {
                int k = kbL + 4*b + i;
                float s0 = rl(h1_0, k), s1 = rl(h1_1, k);
                a0_0 = fmaf(f4e(u0,i), s0, a0_0); a0_1 = fmaf(f4e(u0,i), s1, a0_1);
                a1_0 = fmaf(f4e(u1,i), s0, a1_0); a1_1 = fmaf(f4e(u1,i), s1, a1_1);
                a2_0 = fmaf(f4e(u2,i), s0, a2_0); a2_1 = fmaf(f4e(u2,i), s1, a2_1);
                a3_0 = fmaf(f4e(u3,i), s0, a3_0); a3_1 = fmaf(f4e(u3,i), s1, a3_1);
            }
        }
        EXCHL(h1_0, h1_1, c1my)

        // ---------------- layer 2 ----------------
        if (wid == 3) {
            a0_0=a0_1=b2_0; a1_0=a1_1=b2_1; a2_0=a2_1=b2_2; a3_0=a3_1=b2_3;
        } else {
            a0_0=a1_0=a2_0=a3_0=a0_1=a1_1=a2_1=a3_1=0.f;
        }
        L13(P2)
        EXCHL(h2_0, h2_1, c2my)

        // ---------------- layer 3 ----------------
        if (wid == 3) {
            a0_0=a0_1=b3_0; a1_0=a1_1=b3_1; a2_0=a2_1=b3_2; a3_0=a3_1=b3_3;
        } else {
            a0_0=a1_0=a2_0=a3_0=a0_1=a1_1=a2_1=a3_1=0.f;
        }
        for (int b = 0; b < nbL; ++b) {
            float4 uf = A3f[b], ug = A3g[b], uo = A3o[b];
#pragma unroll
            for (int i = 0; i < 4; ++i) {
                int k = kbL + 4*b + i;
                float s0 = rl(h2_0, k), s1 = rl(h2_1, k);
                a1_0 = fmaf(f4e(uf,i), s0, a1_0); a1_1 = fmaf(f4e(uf,i), s1, a1_1);
                a2_0 = fmaf(f4e(ug,i), s0, a2_0); a2_1 = fmaf(f4e(ug,i), s1, a2_1);
                a3_0 = fmaf(f4e(uo,i), s0, a3_0); a3_1 = fmaf(f4e(uo,i), s1, a3_1);
            }
        }
        L13(P3)
        EXCHL(h3_0, h3_1, c3my)

        // ---------------- head: wave 3 only ----------------
        if (wid == 3) {
            float s0 = wlinr * h3_0; RED(s0) float ov0 = s0 + blinr;
            float s1 = wlinr * h3_1; RED(s1) float ov1 = s1 + blinr;
            xf0 = ov0; xf1 = ov1;
            if (lane == 0) {
                if (is16) { o16w0[t] = f2bf(ov0); o16w1[t] = f2bf(ov1); }
                else      { o32w0[t] = ov0;       o32w1[t] = ov1; }
            }
        }
    }
}

extern "C" void kernel_launch(void* const* d_in, const int* in_sizes, int n_in,
                              void* d_out, int out_size, void* d_ws, size_t ws_size,
                              hipStream_t stream) {
    (void)in_sizes; (void)n_in; (void)d_ws; (void)ws_size; (void)out_size;
    size_t shmem = LDSFL * sizeof(float);   // 81,328 B -> 2 blocks/CU
    hipFuncSetAttribute((const void*)lstm3_kernel,
                        hipFuncAttributeMaxDynamicSharedMemorySize, (int)shmem);
    lstm3_kernel<<<dim3(512), dim3(256), shmem, stream>>>(
        d_in[0],  d_in[1],  d_in[2],  d_in[3],  d_in[4],
        d_in[5],  d_in[6],  d_in[7],  d_in[8],
        d_in[9],  d_in[10], d_in[11], d_in[12],
        d_in[13], d_in[14], d_out);
}